// Round 12
// baseline (781.617 us; speedup 1.0000x reference)
//
#include <hip/hip_runtime.h>

#define IN_DIM 128
#define HID_DIM 256
#define OUT_DIM 128
#define KHOPS 10

#define NB2 256       // bucket array size; buckets = dst>>9 (512 nodes), 196 used
#define NBLK_B 640    // blocks for bucket passes
#define CAP2 12288    // LDS col capacity per bucket (mean 8163, +45 sigma)

typedef __attribute__((ext_vector_type(8))) short bf16x8;
typedef __attribute__((ext_vector_type(4))) float f32x4;

// bf16 round-to-nearest-even from fp32
__device__ __forceinline__ unsigned short f2bf(float x) {
    unsigned int b = __float_as_uint(x);
    unsigned int r = (b + 0x7FFFu + ((b >> 16) & 1u)) >> 16;
    return (unsigned short)r;
}
__device__ __forceinline__ unsigned int pack_bf2(float lo, float hi) {
    return (unsigned int)f2bf(lo) | ((unsigned int)f2bf(hi) << 16);
}
__device__ __forceinline__ float bf_lo(unsigned int u) { return __uint_as_float(u << 16); }
__device__ __forceinline__ float bf_hi(unsigned int u) { return __uint_as_float(u & 0xFFFF0000u); }

// ---------------- CSR build (fine-bucket counting sort, fused pass B) ----------------
// pairs packed: src (17 bits) | (dst & 511) << 17

__global__ void zero_buckets(int* __restrict__ bucket_cnt) {
    if (threadIdx.x < NB2) bucket_cnt[threadIdx.x] = 0;
}

// pass A1: per-block bucket histogram; reserve per-block ranges
__global__ __launch_bounds__(256) void bucket_count(
    const int* __restrict__ dst, int* __restrict__ bucket_cnt,
    int* __restrict__ blk_base, int E) {
    __shared__ int h[NB2];
    int tid = threadIdx.x;
    h[tid] = 0;
    __syncthreads();
    for (int e = blockIdx.x * 256 + tid; e < E; e += NBLK_B * 256)
        atomicAdd(&h[dst[e] >> 9], 1);
    __syncthreads();
    blk_base[blockIdx.x * NB2 + tid] = atomicAdd(&bucket_cnt[tid], h[tid]);
}

// pass A2: exclusive scan of the NB2 bucket counts
__global__ void bucket_scan(const int* __restrict__ bucket_cnt,
                            int* __restrict__ bucket_start) {
    __shared__ int s[NB2];
    int tid = threadIdx.x;   // NB2 threads
    int v = bucket_cnt[tid];
    s[tid] = v;
    __syncthreads();
    for (int off = 1; off < NB2; off <<= 1) {
        int t = (tid >= off) ? s[tid - off] : 0;
        __syncthreads();
        s[tid] += t;
        __syncthreads();
    }
    bucket_start[tid] = s[tid] - v;
}

// pass A3: write packed pairs into bucket-ordered array (per-block reserved ranges)
__global__ __launch_bounds__(256) void bucket_fill(
    const int* __restrict__ src, const int* __restrict__ dst,
    const int* __restrict__ bucket_start, const int* __restrict__ blk_base,
    unsigned int* __restrict__ pairs, int E) {
    __shared__ int base[NB2];
    int tid = threadIdx.x;
    base[tid] = bucket_start[tid] + blk_base[blockIdx.x * NB2 + tid];
    __syncthreads();
    for (int e = blockIdx.x * 256 + tid; e < E; e += NBLK_B * 256) {
        int d = dst[e], s = src[e];
        int p = atomicAdd(&base[d >> 9], 1);
        pairs[p] = (unsigned int)s | ((unsigned int)(d & 511) << 17);
    }
}

// pass B (fused): one block per bucket (512 nodes). Histogram + scan + row_ptr +
// norm + LDS col scatter + coalesced stream-out.
__global__ __launch_bounds__(512) void build_csr(
    const unsigned int* __restrict__ pairs, const int* __restrict__ bucket_start,
    int* __restrict__ row_ptr, float* __restrict__ norm, int* __restrict__ col,
    int N, int E) {
    int bk = blockIdx.x;
    int node0 = bk << 9;
    int nn = min(512, N - node0);
    int ebeg = bucket_start[bk];
    int eend = (bk + 1 < NB2) ? bucket_start[bk + 1] : E;
    __shared__ int hist[512];
    __shared__ int sc[512];
    __shared__ int lcol[CAP2];
    int tid = threadIdx.x;
    hist[tid] = 0;
    __syncthreads();
    for (int e = ebeg + tid; e < eend; e += 512)
        atomicAdd(&hist[pairs[e] >> 17], 1);
    __syncthreads();
    int deg = hist[tid];
    sc[tid] = deg;
    __syncthreads();
    for (int off = 1; off < 512; off <<= 1) {
        int t = (tid >= off) ? sc[tid - off] : 0;
        __syncthreads();
        sc[tid] += t;
        __syncthreads();
    }
    int excl = sc[tid] - deg;        // bucket-local exclusive scan
    if (tid < nn) {
        row_ptr[node0 + tid] = ebeg + excl;
        norm[node0 + tid] = rsqrtf((float)(deg + 1));
    }
    hist[tid] = excl;                // reuse as running fill position
    __syncthreads();
    for (int e = ebeg + tid; e < eend; e += 512) {
        unsigned int p = pairs[e];
        int dlow = p >> 17;
        int pos = atomicAdd(&hist[dlow], 1);
        int s = (int)(p & 0x1FFFFu);
        if (pos < CAP2) lcol[pos] = s;
        else col[ebeg + pos] = s;    // statistical never; correctness guard
    }
    __syncthreads();
    int tot = eend - ebeg;
    int n_out = tot < CAP2 ? tot : CAP2;
    for (int i = tid; i < n_out; i += 512) col[ebeg + i] = lcol[i];
    if (bk == 0 && tid == 0) row_ptr[N] = E;
}

// ---------------- weight pre-swizzle (frag-major bf16, both in one kernel) ----------------
// index space: 32768 (W1s) + 32768 (W2s) = 65536 -> MUST launch 256 blocks x 256.

__global__ void pack_weights(const float* __restrict__ W1, short* __restrict__ W1s,
                             const float* __restrict__ W2, short* __restrict__ W2s) {
    int i = blockIdx.x * 256 + threadIdx.x;
    if (i < 16 * 4 * 64 * 8) {
        int j = i & 7, l = (i >> 3) & 63, kf = (i >> 9) & 3, rf = i >> 11;
        int k = kf * 32 + (l >> 4) * 8 + j;   // in-feat  0..127
        int r = rf * 16 + (l & 15);           // hid-feat 0..255
        W1s[i] = (short)f2bf(W1[(size_t)k * HID_DIM + r]);
    }
    int i2 = i - 16 * 4 * 64 * 8;
    if (i2 >= 0 && i2 < 8 * 8 * 64 * 8) {
        int j = i2 & 7, l = (i2 >> 3) & 63, kf = (i2 >> 9) & 7, rf = i2 >> 12;
        int k = kf * 32 + (l >> 4) * 8 + j;   // hid-feat 0..255
        int r = rf * 16 + (l & 15);           // out-feat 0..127
        W2s[i2] = (short)f2bf(W2[(size_t)k * OUT_DIM + r]);
    }
}

// ---------------- propagation ----------------
// State lives ONLY as packed bf16 pairs: sh[node*64 + l] = (g[2l], g[2l+1]).
// ffeat[node*64 + l] = packed bf16 of 0.1*norm*feat (the per-hop additive term).

__global__ void init_g(const float* __restrict__ feat, const float* __restrict__ norm,
                       unsigned int* __restrict__ sh, unsigned int* __restrict__ ffeat,
                       int N) {
    int idx = blockIdx.x * blockDim.x + threadIdx.x;   // one bf16-pair per thread
    int total = N * 64;
    if (idx >= total) return;
    int row = idx >> 6;
    int l   = idx & 63;
    float nr = norm[row];
    float2 f = *(const float2*)(feat + (size_t)row * IN_DIM + l * 2);
    sh[idx]    = pack_bf2(nr * f.x, nr * f.y);
    ffeat[idx] = pack_bf2(0.1f * nr * f.x, 0.1f * nr * f.y);
}

// one full wave per dst node; lane owns dims (2l, 2l+1) as one packed uint.
// Non-temporal on the zero-reuse streams (sh_out store, ffeat/col loads) so L2
// keeps sh_in lines, which each get re-gathered ~16x per hop.
__global__ __launch_bounds__(256) void hop_kernel(
    const unsigned int* __restrict__ sh_in, unsigned int* __restrict__ sh_out,
    const unsigned int* __restrict__ ffeat, const float* __restrict__ norm,
    const int* __restrict__ row_ptr, const int* __restrict__ col,
    int N) {
    int node = __builtin_amdgcn_readfirstlane(blockIdx.x * 4 + (threadIdx.x >> 6));
    int lane = threadIdx.x & 63;
    if (node >= N) return;
    size_t base = (size_t)node * 64 + lane;
    unsigned int uself = sh_in[base];
    float2 acc = { bf_lo(uself), bf_hi(uself) };       // self loop
    int beg = row_ptr[node], end = row_ptr[node + 1];  // scalar loads
    int e = beg;
    for (; e + 7 < end; e += 8) {
        int s0 = __builtin_nontemporal_load(col + e);
        int s1 = __builtin_nontemporal_load(col + e + 1);
        int s2 = __builtin_nontemporal_load(col + e + 2);
        int s3 = __builtin_nontemporal_load(col + e + 3);
        int s4 = __builtin_nontemporal_load(col + e + 4);
        int s5 = __builtin_nontemporal_load(col + e + 5);
        int s6 = __builtin_nontemporal_load(col + e + 6);
        int s7 = __builtin_nontemporal_load(col + e + 7);
        unsigned int u0 = sh_in[(size_t)s0 * 64 + lane];
        unsigned int u1 = sh_in[(size_t)s1 * 64 + lane];
        unsigned int u2 = sh_in[(size_t)s2 * 64 + lane];
        unsigned int u3 = sh_in[(size_t)s3 * 64 + lane];
        unsigned int u4 = sh_in[(size_t)s4 * 64 + lane];
        unsigned int u5 = sh_in[(size_t)s5 * 64 + lane];
        unsigned int u6 = sh_in[(size_t)s6 * 64 + lane];
        unsigned int u7 = sh_in[(size_t)s7 * 64 + lane];
        acc.x += (bf_lo(u0) + bf_lo(u1)) + (bf_lo(u2) + bf_lo(u3))
               + (bf_lo(u4) + bf_lo(u5)) + (bf_lo(u6) + bf_lo(u7));
        acc.y += (bf_hi(u0) + bf_hi(u1)) + (bf_hi(u2) + bf_hi(u3))
               + (bf_hi(u4) + bf_hi(u5)) + (bf_hi(u6) + bf_hi(u7));
    }
    for (; e < end; ++e) {
        int s0 = __builtin_nontemporal_load(col + e);
        unsigned int u = sh_in[(size_t)s0 * 64 + lane];
        acc.x += bf_lo(u);
        acc.y += bf_hi(u);
    }
    float nr = norm[node];
    float c1 = 0.9f * nr * nr;
    unsigned int uff = __builtin_nontemporal_load(ffeat + base);
    float ox = c1 * acc.x + bf_lo(uff);
    float oy = c1 * acc.y + bf_hi(uff);
    __builtin_nontemporal_store(pack_bf2(ox, oy), sh_out + base);
}

// ---------------- fused MLP via bf16 MFMA ----------------
// Computes transposed: hidT = W1T@AhT, outT = W2T@hidT. 64 nodes/block, 4 waves.

#define LDA 136   // Ah row stride (bf16)
#define LDH 264   // Hid row stride (bf16)

__global__ __launch_bounds__(256) void mlp_mfma(
    const unsigned int* __restrict__ sh, const float* __restrict__ norm,
    const short* __restrict__ W1s, const float* __restrict__ b1,
    const short* __restrict__ W2s, const float* __restrict__ b2,
    float* __restrict__ out, int N)
{
    __shared__ short Ah[64 * LDA];    // 17408 B, h = unpack(sh)/norm, bf16
    __shared__ short Hid[64 * LDH];   // 33792 B, relu(h@W1+b1), bf16
    int tid  = threadIdx.x;
    int wid  = tid >> 6;
    int lane = tid & 63;
    int row0 = blockIdx.x * 64;

    // ---- stage Ah (64 rows x 64 packed uints) ----
    for (int i = tid; i < 64 * 64; i += 256) {
        int r = i >> 6, c = i & 63;
        int row = row0 + r;
        unsigned int u = 0;
        float inv = 1.f;
        if (row < N) { u = sh[(size_t)row * 64 + c]; inv = 1.0f / norm[row]; }
        *(unsigned int*)&Ah[r * LDA + c * 2] = pack_bf2(bf_lo(u) * inv, bf_hi(u) * inv);
    }
    __syncthreads();

    int m = lane & 15;        // node-in-frag / feat row lane
    int g = lane >> 4;        // k-group

    // ---- GEMM1: wave w -> hid feats [w*64, w*64+64), all 64 nodes ----
    {
        bf16x8 Bf[4][4];      // [kf][cf] from Ah
        #pragma unroll
        for (int kf = 0; kf < 4; ++kf)
            #pragma unroll
            for (int cf = 0; cf < 4; ++cf)
                Bf[kf][cf] = *(const bf16x8*)&Ah[(cf * 16 + m) * LDA + kf * 32 + g * 8];

        f32x4 acc[4][4];      // [rf_local][cf]
        #pragma unroll
        for (int i = 0; i < 4; ++i)
            #pragma unroll
            for (int cf = 0; cf < 4; ++cf)
                acc[i][cf] = (f32x4){0.f, 0.f, 0.f, 0.f};

        #pragma unroll
        for (int i = 0; i < 4; ++i) {
            int rf = wid * 4 + i;
            #pragma unroll
            for (int kf = 0; kf < 4; ++kf) {
                bf16x8 Af = *(const bf16x8*)(W1s + (((size_t)(rf * 4 + kf)) * 64 + lane) * 8);
                #pragma unroll
                for (int cf = 0; cf < 4; ++cf)
                    acc[i][cf] = __builtin_amdgcn_mfma_f32_16x16x32_bf16(
                        Af, Bf[kf][cf], acc[i][cf], 0, 0, 0);
            }
        }

        // bias + relu + bf16 -> Hid LDS (4 consecutive feats per lane)
        #pragma unroll
        for (int i = 0; i < 4; ++i) {
            int feat0 = (wid * 4 + i) * 16 + g * 4;
            float4 bias = *(const float4*)(b1 + feat0);
            #pragma unroll
            for (int cf = 0; cf < 4; ++cf) {
                int node = cf * 16 + m;
                float v0 = acc[i][cf][0] + bias.x; v0 = v0 > 0.f ? v0 : 0.f;
                float v1 = acc[i][cf][1] + bias.y; v1 = v1 > 0.f ? v1 : 0.f;
                float v2 = acc[i][cf][2] + bias.z; v2 = v2 > 0.f ? v2 : 0.f;
                float v3 = acc[i][cf][3] + bias.w; v3 = v3 > 0.f ? v3 : 0.f;
                uint2 p;
                p.x = pack_bf2(v0, v1);
                p.y = pack_bf2(v2, v3);
                *(uint2*)&Hid[node * LDH + feat0] = p;   // ds_write_b64
            }
        }
    }
    __syncthreads();

    // ---- GEMM2: wave w -> out feats [w*32, w*32+32), all 64 nodes ----
    {
        f32x4 acc2[2][4];
        #pragma unroll
        for (int i = 0; i < 2; ++i)
            #pragma unroll
            for (int cf = 0; cf < 4; ++cf)
                acc2[i][cf] = (f32x4){0.f, 0.f, 0.f, 0.f};

        #pragma unroll
        for (int kf = 0; kf < 8; ++kf) {
            bf16x8 Bh[4];
            #pragma unroll
            for (int cf = 0; cf < 4; ++cf)
                Bh[cf] = *(const bf16x8*)&Hid[(cf * 16 + m) * LDH + kf * 32 + g * 8];
            #pragma unroll
            for (int i = 0; i < 2; ++i) {
                int rf = wid * 2 + i;
                bf16x8 Af = *(const bf16x8*)(W2s + (((size_t)(rf * 8 + kf)) * 64 + lane) * 8);
                #pragma unroll
                for (int cf = 0; cf < 4; ++cf)
                    acc2[i][cf] = __builtin_amdgcn_mfma_f32_16x16x32_bf16(
                        Af, Bh[cf], acc2[i][cf], 0, 0, 0);
            }
        }

        #pragma unroll
        for (int i = 0; i < 2; ++i) {
            int feat0 = (wid * 2 + i) * 16 + g * 4;
            float4 bias = *(const float4*)(b2 + feat0);
            #pragma unroll
            for (int cf = 0; cf < 4; ++cf) {
                int node = row0 + cf * 16 + m;
                if (node < N) {
                    float4 o;
                    o.x = acc2[i][cf][0] + bias.x;
                    o.y = acc2[i][cf][1] + bias.y;
                    o.z = acc2[i][cf][2] + bias.z;
                    o.w = acc2[i][cf][3] + bias.w;
                    *(float4*)(out + (size_t)node * OUT_DIM + feat0) = o;
                }
            }
        }
    }
}

// ---------------- launch ----------------

extern "C" void kernel_launch(void* const* d_in, const int* in_sizes, int n_in,
                              void* d_out, int out_size, void* d_ws, size_t ws_size,
                              hipStream_t stream) {
    const float* feat = (const float*)d_in[0];
    const float* W1   = (const float*)d_in[1];
    const float* b1   = (const float*)d_in[2];
    const float* W2   = (const float*)d_in[3];
    const float* b2   = (const float*)d_in[4];
    const int*   src  = (const int*)d_in[5];
    const int*   dst  = (const int*)d_in[6];
    float* out = (float*)d_out;

    int N = in_sizes[0] / IN_DIM;     // 100000
    int E = in_sizes[5];              // 1600000

    // workspace carve (256B aligned)
    size_t off = 0;
    auto carve = [&](size_t bytes) -> void* {
        void* p = (char*)d_ws + off;
        off += (bytes + 255) & ~(size_t)255;
        return p;
    };
    float* norm    = (float*)carve((size_t)N * 4);
    int*   row_ptr = (int*)carve((size_t)(N + 1) * 4);
    int*   col     = (int*)carve((size_t)E * 4);
    unsigned int* shA   = (unsigned int*)carve((size_t)N * 64 * 4);  // bf16 state ping
    unsigned int* shB   = (unsigned int*)carve((size_t)N * 64 * 4);  // bf16 state pong
    unsigned int* ffeat = (unsigned int*)carve((size_t)N * 64 * 4);  // bf16 0.1*norm*feat
    short* W1s = (short*)carve((size_t)16 * 4 * 64 * 8 * 2);
    short* W2s = (short*)carve((size_t)8 * 8 * 64 * 8 * 2);
    int*   bucket_cnt   = (int*)carve(NB2 * 4);
    int*   bucket_start = (int*)carve(NB2 * 4);
    int*   blk_base     = (int*)carve((size_t)NBLK_B * NB2 * 4);
    unsigned int* pairs = (unsigned int*)carve((size_t)E * 4);
    (void)ws_size;

    int nbBK = (N + 511) >> 9;        // 196 buckets

    zero_buckets<<<1, NB2, 0, stream>>>(bucket_cnt);
    bucket_count<<<NBLK_B, 256, 0, stream>>>(dst, bucket_cnt, blk_base, E);
    bucket_scan<<<1, NB2, 0, stream>>>(bucket_cnt, bucket_start);
    bucket_fill<<<NBLK_B, 256, 0, stream>>>(src, dst, bucket_start, blk_base, pairs, E);
    build_csr<<<nbBK, 512, 0, stream>>>(pairs, bucket_start, row_ptr, norm, col, N, E);

    pack_weights<<<256, 256, 0, stream>>>(W1, W1s, W2, W2s);   // 65536 threads: full cover

    int nbG = ((size_t)N * 64 + 255) / 256;
    init_g<<<nbG, 256, 0, stream>>>(feat, norm, shA, ffeat, N);

    // one wave per node, 4 nodes per block
    int nbHop = (N + 3) / 4;
    for (int t = 0; t < KHOPS; ++t) {
        const unsigned int* si = (t % 2 == 0) ? shA : shB;
        unsigned int*       so = (t % 2 == 0) ? shB : shA;
        hop_kernel<<<nbHop, 256, 0, stream>>>(si, so, ffeat, norm, row_ptr, col, N);
    }
    // after 10 hops (even count), final state is in shA

    int nbM = (N + 63) / 64;
    mlp_mfma<<<nbM, 256, 0, stream>>>(shA, norm, W1s, b1, W2s, b2, out, N);
}

// Round 13
// 721.829 us; speedup vs baseline: 1.0828x; 1.0828x over previous
//
#include <hip/hip_runtime.h>

#define IN_DIM 128
#define HID_DIM 256
#define OUT_DIM 128
#define KHOPS 10

#define NB2 256       // bucket array size; buckets = dst>>9 (512 nodes), 196 used
#define NBLK_B 640    // blocks for bucket passes
#define CAP2 12288    // LDS col capacity per bucket (mean 8163, +45 sigma)

typedef __attribute__((ext_vector_type(8))) short bf16x8;
typedef __attribute__((ext_vector_type(4))) float f32x4;

// bf16 round-to-nearest-even from fp32
__device__ __forceinline__ unsigned short f2bf(float x) {
    unsigned int b = __float_as_uint(x);
    unsigned int r = (b + 0x7FFFu + ((b >> 16) & 1u)) >> 16;
    return (unsigned short)r;
}
__device__ __forceinline__ unsigned int pack_bf2(float lo, float hi) {
    return (unsigned int)f2bf(lo) | ((unsigned int)f2bf(hi) << 16);
}
__device__ __forceinline__ float bf_lo(unsigned int u) { return __uint_as_float(u << 16); }
__device__ __forceinline__ float bf_hi(unsigned int u) { return __uint_as_float(u & 0xFFFF0000u); }

// ---------------- CSR build (fine-bucket counting sort, fused pass B) ----------------
// pairs packed: src (17 bits) | (dst & 511) << 17

__global__ void zero_buckets(int* __restrict__ bucket_cnt) {
    if (threadIdx.x < NB2) bucket_cnt[threadIdx.x] = 0;
}

// pass A1: per-block bucket histogram; reserve per-block ranges
__global__ __launch_bounds__(256) void bucket_count(
    const int* __restrict__ dst, int* __restrict__ bucket_cnt,
    int* __restrict__ blk_base, int E) {
    __shared__ int h[NB2];
    int tid = threadIdx.x;
    h[tid] = 0;
    __syncthreads();
    for (int e = blockIdx.x * 256 + tid; e < E; e += NBLK_B * 256)
        atomicAdd(&h[dst[e] >> 9], 1);
    __syncthreads();
    blk_base[blockIdx.x * NB2 + tid] = atomicAdd(&bucket_cnt[tid], h[tid]);
}

// pass A2: exclusive scan of the NB2 bucket counts
__global__ void bucket_scan(const int* __restrict__ bucket_cnt,
                            int* __restrict__ bucket_start) {
    __shared__ int s[NB2];
    int tid = threadIdx.x;   // NB2 threads
    int v = bucket_cnt[tid];
    s[tid] = v;
    __syncthreads();
    for (int off = 1; off < NB2; off <<= 1) {
        int t = (tid >= off) ? s[tid - off] : 0;
        __syncthreads();
        s[tid] += t;
        __syncthreads();
    }
    bucket_start[tid] = s[tid] - v;
}

// pass A3: write packed pairs into bucket-ordered array (per-block reserved ranges)
__global__ __launch_bounds__(256) void bucket_fill(
    const int* __restrict__ src, const int* __restrict__ dst,
    const int* __restrict__ bucket_start, const int* __restrict__ blk_base,
    unsigned int* __restrict__ pairs, int E) {
    __shared__ int base[NB2];
    int tid = threadIdx.x;
    base[tid] = bucket_start[tid] + blk_base[blockIdx.x * NB2 + tid];
    __syncthreads();
    for (int e = blockIdx.x * 256 + tid; e < E; e += NBLK_B * 256) {
        int d = dst[e], s = src[e];
        int p = atomicAdd(&base[d >> 9], 1);
        pairs[p] = (unsigned int)s | ((unsigned int)(d & 511) << 17);
    }
}

// pass B (fused): one block per bucket (512 nodes). Histogram + scan + row_ptr +
// norm + LDS col scatter + coalesced stream-out.
__global__ __launch_bounds__(512) void build_csr(
    const unsigned int* __restrict__ pairs, const int* __restrict__ bucket_start,
    int* __restrict__ row_ptr, float* __restrict__ norm, int* __restrict__ col,
    int N, int E) {
    int bk = blockIdx.x;
    int node0 = bk << 9;
    int nn = min(512, N - node0);
    int ebeg = bucket_start[bk];
    int eend = (bk + 1 < NB2) ? bucket_start[bk + 1] : E;
    __shared__ int hist[512];
    __shared__ int sc[512];
    __shared__ int lcol[CAP2];
    int tid = threadIdx.x;
    hist[tid] = 0;
    __syncthreads();
    for (int e = ebeg + tid; e < eend; e += 512)
        atomicAdd(&hist[pairs[e] >> 17], 1);
    __syncthreads();
    int deg = hist[tid];
    sc[tid] = deg;
    __syncthreads();
    for (int off = 1; off < 512; off <<= 1) {
        int t = (tid >= off) ? sc[tid - off] : 0;
        __syncthreads();
        sc[tid] += t;
        __syncthreads();
    }
    int excl = sc[tid] - deg;        // bucket-local exclusive scan
    if (tid < nn) {
        row_ptr[node0 + tid] = ebeg + excl;
        norm[node0 + tid] = rsqrtf((float)(deg + 1));
    }
    hist[tid] = excl;                // reuse as running fill position
    __syncthreads();
    for (int e = ebeg + tid; e < eend; e += 512) {
        unsigned int p = pairs[e];
        int dlow = p >> 17;
        int pos = atomicAdd(&hist[dlow], 1);
        int s = (int)(p & 0x1FFFFu);
        if (pos < CAP2) lcol[pos] = s;
        else col[ebeg + pos] = s;    // statistical never; correctness guard
    }
    __syncthreads();
    int tot = eend - ebeg;
    int n_out = tot < CAP2 ? tot : CAP2;
    for (int i = tid; i < n_out; i += 512) col[ebeg + i] = lcol[i];
    if (bk == 0 && tid == 0) row_ptr[N] = E;
}

// ---------------- weight pre-swizzle (frag-major bf16, both in one kernel) ----------------
// index space: 32768 (W1s) + 32768 (W2s) = 65536 -> MUST launch 256 blocks x 256.

__global__ void pack_weights(const float* __restrict__ W1, short* __restrict__ W1s,
                             const float* __restrict__ W2, short* __restrict__ W2s) {
    int i = blockIdx.x * 256 + threadIdx.x;
    if (i < 16 * 4 * 64 * 8) {
        int j = i & 7, l = (i >> 3) & 63, kf = (i >> 9) & 3, rf = i >> 11;
        int k = kf * 32 + (l >> 4) * 8 + j;   // in-feat  0..127
        int r = rf * 16 + (l & 15);           // hid-feat 0..255
        W1s[i] = (short)f2bf(W1[(size_t)k * HID_DIM + r]);
    }
    int i2 = i - 16 * 4 * 64 * 8;
    if (i2 >= 0 && i2 < 8 * 8 * 64 * 8) {
        int j = i2 & 7, l = (i2 >> 3) & 63, kf = (i2 >> 9) & 7, rf = i2 >> 12;
        int k = kf * 32 + (l >> 4) * 8 + j;   // hid-feat 0..255
        int r = rf * 16 + (l & 15);           // out-feat 0..127
        W2s[i2] = (short)f2bf(W2[(size_t)k * OUT_DIM + r]);
    }
}

// ---------------- propagation ----------------
// State lives ONLY as packed bf16 pairs: sh[node*64 + l] = (g[2l], g[2l+1]).
// ffeat[node*64 + l] = packed bf16 of 0.1*norm*feat (the per-hop additive term).

__global__ void init_g(const float* __restrict__ feat, const float* __restrict__ norm,
                       unsigned int* __restrict__ sh, unsigned int* __restrict__ ffeat,
                       int N) {
    int idx = blockIdx.x * blockDim.x + threadIdx.x;   // one bf16-pair per thread
    int total = N * 64;
    if (idx >= total) return;
    int row = idx >> 6;
    int l   = idx & 63;
    float nr = norm[row];
    float2 f = *(const float2*)(feat + (size_t)row * IN_DIM + l * 2);
    sh[idx]    = pack_bf2(nr * f.x, nr * f.y);
    ffeat[idx] = pack_bf2(0.1f * nr * f.x, 0.1f * nr * f.y);
}

// one full wave per dst node; lane owns dims (2l, 2l+1) as one packed uint.
// 16-deep gather unroll: 16 outstanding 256B row-gathers per wave (concurrency,
// not BW, appears to limit: 3.6 of 6.3 TB/s at VALUBusy 20%).
__global__ __launch_bounds__(256) void hop_kernel(
    const unsigned int* __restrict__ sh_in, unsigned int* __restrict__ sh_out,
    const unsigned int* __restrict__ ffeat, const float* __restrict__ norm,
    const int* __restrict__ row_ptr, const int* __restrict__ col,
    int N) {
    int node = __builtin_amdgcn_readfirstlane(blockIdx.x * 4 + (threadIdx.x >> 6));
    int lane = threadIdx.x & 63;
    if (node >= N) return;
    size_t base = (size_t)node * 64 + lane;
    unsigned int uself = sh_in[base];
    float2 acc = { bf_lo(uself), bf_hi(uself) };       // self loop
    int beg = row_ptr[node], end = row_ptr[node + 1];  // scalar loads
    int e = beg;
    for (; e + 15 < end; e += 16) {
        unsigned int u[16];
        #pragma unroll
        for (int q = 0; q < 16; ++q) {
            int s = col[e + q];
            u[q] = sh_in[(size_t)s * 64 + lane];
        }
        float ax = 0.f, ay = 0.f;
        #pragma unroll
        for (int q = 0; q < 16; ++q) { ax += bf_lo(u[q]); ay += bf_hi(u[q]); }
        acc.x += ax;
        acc.y += ay;
    }
    for (; e + 3 < end; e += 4) {
        unsigned int u[4];
        #pragma unroll
        for (int q = 0; q < 4; ++q) {
            int s = col[e + q];
            u[q] = sh_in[(size_t)s * 64 + lane];
        }
        acc.x += (bf_lo(u[0]) + bf_lo(u[1])) + (bf_lo(u[2]) + bf_lo(u[3]));
        acc.y += (bf_hi(u[0]) + bf_hi(u[1])) + (bf_hi(u[2]) + bf_hi(u[3]));
    }
    for (; e < end; ++e) {
        unsigned int u = sh_in[(size_t)col[e] * 64 + lane];
        acc.x += bf_lo(u);
        acc.y += bf_hi(u);
    }
    float nr = norm[node];
    float c1 = 0.9f * nr * nr;
    unsigned int uff = ffeat[base];
    float ox = c1 * acc.x + bf_lo(uff);
    float oy = c1 * acc.y + bf_hi(uff);
    sh_out[base] = pack_bf2(ox, oy);
}

// ---------------- fused MLP via bf16 MFMA ----------------
// Computes transposed: hidT = W1T@AhT, outT = W2T@hidT. 64 nodes/block, 4 waves.

#define LDA 136   // Ah row stride (bf16)
#define LDH 264   // Hid row stride (bf16)

__global__ __launch_bounds__(256) void mlp_mfma(
    const unsigned int* __restrict__ sh, const float* __restrict__ norm,
    const short* __restrict__ W1s, const float* __restrict__ b1,
    const short* __restrict__ W2s, const float* __restrict__ b2,
    float* __restrict__ out, int N)
{
    __shared__ short Ah[64 * LDA];    // 17408 B, h = unpack(sh)/norm, bf16
    __shared__ short Hid[64 * LDH];   // 33792 B, relu(h@W1+b1), bf16
    int tid  = threadIdx.x;
    int wid  = tid >> 6;
    int lane = tid & 63;
    int row0 = blockIdx.x * 64;

    // ---- stage Ah (64 rows x 64 packed uints) ----
    for (int i = tid; i < 64 * 64; i += 256) {
        int r = i >> 6, c = i & 63;
        int row = row0 + r;
        unsigned int u = 0;
        float inv = 1.f;
        if (row < N) { u = sh[(size_t)row * 64 + c]; inv = 1.0f / norm[row]; }
        *(unsigned int*)&Ah[r * LDA + c * 2] = pack_bf2(bf_lo(u) * inv, bf_hi(u) * inv);
    }
    __syncthreads();

    int m = lane & 15;        // node-in-frag / feat row lane
    int g = lane >> 4;        // k-group

    // ---- GEMM1: wave w -> hid feats [w*64, w*64+64), all 64 nodes ----
    {
        bf16x8 Bf[4][4];      // [kf][cf] from Ah
        #pragma unroll
        for (int kf = 0; kf < 4; ++kf)
            #pragma unroll
            for (int cf = 0; cf < 4; ++cf)
                Bf[kf][cf] = *(const bf16x8*)&Ah[(cf * 16 + m) * LDA + kf * 32 + g * 8];

        f32x4 acc[4][4];      // [rf_local][cf]
        #pragma unroll
        for (int i = 0; i < 4; ++i)
            #pragma unroll
            for (int cf = 0; cf < 4; ++cf)
                acc[i][cf] = (f32x4){0.f, 0.f, 0.f, 0.f};

        #pragma unroll
        for (int i = 0; i < 4; ++i) {
            int rf = wid * 4 + i;
            #pragma unroll
            for (int kf = 0; kf < 4; ++kf) {
                bf16x8 Af = *(const bf16x8*)(W1s + (((size_t)(rf * 4 + kf)) * 64 + lane) * 8);
                #pragma unroll
                for (int cf = 0; cf < 4; ++cf)
                    acc[i][cf] = __builtin_amdgcn_mfma_f32_16x16x32_bf16(
                        Af, Bf[kf][cf], acc[i][cf], 0, 0, 0);
            }
        }

        // bias + relu + bf16 -> Hid LDS (4 consecutive feats per lane)
        #pragma unroll
        for (int i = 0; i < 4; ++i) {
            int feat0 = (wid * 4 + i) * 16 + g * 4;
            float4 bias = *(const float4*)(b1 + feat0);
            #pragma unroll
            for (int cf = 0; cf < 4; ++cf) {
                int node = cf * 16 + m;
                float v0 = acc[i][cf][0] + bias.x; v0 = v0 > 0.f ? v0 : 0.f;
                float v1 = acc[i][cf][1] + bias.y; v1 = v1 > 0.f ? v1 : 0.f;
                float v2 = acc[i][cf][2] + bias.z; v2 = v2 > 0.f ? v2 : 0.f;
                float v3 = acc[i][cf][3] + bias.w; v3 = v3 > 0.f ? v3 : 0.f;
                uint2 p;
                p.x = pack_bf2(v0, v1);
                p.y = pack_bf2(v2, v3);
                *(uint2*)&Hid[node * LDH + feat0] = p;   // ds_write_b64
            }
        }
    }
    __syncthreads();

    // ---- GEMM2: wave w -> out feats [w*32, w*32+32), all 64 nodes ----
    {
        f32x4 acc2[2][4];
        #pragma unroll
        for (int i = 0; i < 2; ++i)
            #pragma unroll
            for (int cf = 0; cf < 4; ++cf)
                acc2[i][cf] = (f32x4){0.f, 0.f, 0.f, 0.f};

        #pragma unroll
        for (int kf = 0; kf < 8; ++kf) {
            bf16x8 Bh[4];
            #pragma unroll
            for (int cf = 0; cf < 4; ++cf)
                Bh[cf] = *(const bf16x8*)&Hid[(cf * 16 + m) * LDH + kf * 32 + g * 8];
            #pragma unroll
            for (int i = 0; i < 2; ++i) {
                int rf = wid * 2 + i;
                bf16x8 Af = *(const bf16x8*)(W2s + (((size_t)(rf * 8 + kf)) * 64 + lane) * 8);
                #pragma unroll
                for (int cf = 0; cf < 4; ++cf)
                    acc2[i][cf] = __builtin_amdgcn_mfma_f32_16x16x32_bf16(
                        Af, Bh[cf], acc2[i][cf], 0, 0, 0);
            }
        }

        #pragma unroll
        for (int i = 0; i < 2; ++i) {
            int feat0 = (wid * 2 + i) * 16 + g * 4;
            float4 bias = *(const float4*)(b2 + feat0);
            #pragma unroll
            for (int cf = 0; cf < 4; ++cf) {
                int node = row0 + cf * 16 + m;
                if (node < N) {
                    float4 o;
                    o.x = acc2[i][cf][0] + bias.x;
                    o.y = acc2[i][cf][1] + bias.y;
                    o.z = acc2[i][cf][2] + bias.z;
                    o.w = acc2[i][cf][3] + bias.w;
                    *(float4*)(out + (size_t)node * OUT_DIM + feat0) = o;
                }
            }
        }
    }
}

// ---------------- launch ----------------

extern "C" void kernel_launch(void* const* d_in, const int* in_sizes, int n_in,
                              void* d_out, int out_size, void* d_ws, size_t ws_size,
                              hipStream_t stream) {
    const float* feat = (const float*)d_in[0];
    const float* W1   = (const float*)d_in[1];
    const float* b1   = (const float*)d_in[2];
    const float* W2   = (const float*)d_in[3];
    const float* b2   = (const float*)d_in[4];
    const int*   src  = (const int*)d_in[5];
    const int*   dst  = (const int*)d_in[6];
    float* out = (float*)d_out;

    int N = in_sizes[0] / IN_DIM;     // 100000
    int E = in_sizes[5];              // 1600000

    // workspace carve (256B aligned)
    size_t off = 0;
    auto carve = [&](size_t bytes) -> void* {
        void* p = (char*)d_ws + off;
        off += (bytes + 255) & ~(size_t)255;
        return p;
    };
    float* norm    = (float*)carve((size_t)N * 4);
    int*   row_ptr = (int*)carve((size_t)(N + 1) * 4);
    int*   col     = (int*)carve((size_t)E * 4);
    unsigned int* shA   = (unsigned int*)carve((size_t)N * 64 * 4);  // bf16 state ping
    unsigned int* shB   = (unsigned int*)carve((size_t)N * 64 * 4);  // bf16 state pong
    unsigned int* ffeat = (unsigned int*)carve((size_t)N * 64 * 4);  // bf16 0.1*norm*feat
    short* W1s = (short*)carve((size_t)16 * 4 * 64 * 8 * 2);
    short* W2s = (short*)carve((size_t)8 * 8 * 64 * 8 * 2);
    int*   bucket_cnt   = (int*)carve(NB2 * 4);
    int*   bucket_start = (int*)carve(NB2 * 4);
    int*   blk_base     = (int*)carve((size_t)NBLK_B * NB2 * 4);
    unsigned int* pairs = (unsigned int*)carve((size_t)E * 4);
    (void)ws_size;

    int nbBK = (N + 511) >> 9;        // 196 buckets

    zero_buckets<<<1, NB2, 0, stream>>>(bucket_cnt);
    bucket_count<<<NBLK_B, 256, 0, stream>>>(dst, bucket_cnt, blk_base, E);
    bucket_scan<<<1, NB2, 0, stream>>>(bucket_cnt, bucket_start);
    bucket_fill<<<NBLK_B, 256, 0, stream>>>(src, dst, bucket_start, blk_base, pairs, E);
    build_csr<<<nbBK, 512, 0, stream>>>(pairs, bucket_start, row_ptr, norm, col, N, E);

    pack_weights<<<256, 256, 0, stream>>>(W1, W1s, W2, W2s);   // 65536 threads: full cover

    int nbG = ((size_t)N * 64 + 255) / 256;
    init_g<<<nbG, 256, 0, stream>>>(feat, norm, shA, ffeat, N);

    // one wave per node, 4 nodes per block
    int nbHop = (N + 3) / 4;
    for (int t = 0; t < KHOPS; ++t) {
        const unsigned int* si = (t % 2 == 0) ? shA : shB;
        unsigned int*       so = (t % 2 == 0) ? shB : shA;
        hop_kernel<<<nbHop, 256, 0, stream>>>(si, so, ffeat, norm, row_ptr, col, N);
    }
    // after 10 hops (even count), final state is in shA

    int nbM = (N + 63) / 64;
    mlp_mfma<<<nbM, 256, 0, stream>>>(shA, norm, W1s, b1, W2s, b2, out, N);
}